// Round 6
// baseline (161.803 us; speedup 1.0000x reference)
//
#include <hip/hip_runtime.h>
#include <stdint.h>

typedef unsigned short u16;
typedef float f32x4 __attribute__((ext_vector_type(4)));
typedef __bf16 bf16x8 __attribute__((ext_vector_type(8)));

#define DDIM 768
#define NHEAD 12
#define EDIM 64
#define SREAL 2000
#define SPAD 2048
#define NQ 2048
#define NSPLIT 4

__device__ __forceinline__ u16 f2bf(float f) {
    unsigned u = __float_as_uint(f);
    return (u16)((u + 0x7fffu + ((u >> 16) & 1u)) >> 16);
}
__device__ __forceinline__ float bf2f(u16 v) {
    return __uint_as_float(((unsigned)v) << 16);
}

__device__ __forceinline__ void async16(const void* g, void* l) {
    __builtin_amdgcn_global_load_lds(
        (const __attribute__((address_space(1))) void*)(const void*)g,
        (__attribute__((address_space(3))) void*)l, 16, 0, 0);
}

// ---------------- fused: cast weights -> bf16 (Wq pre-scaled by 0.125, incl. Wo) + layernorm ----------------
__global__ __launch_bounds__(256) void prep_kernel(
    const float* __restrict__ Wq, const float* __restrict__ Wk, const float* __restrict__ Wv,
    const float* __restrict__ Wo,
    u16* __restrict__ Wqb, u16* __restrict__ Wkb, u16* __restrict__ Wvb, u16* __restrict__ Wob,
    const float* __restrict__ tgt, const float* __restrict__ keyb, const float* __restrict__ valb,
    const float* __restrict__ g_q, const float* __restrict__ b_q,
    const float* __restrict__ g_kv, const float* __restrict__ b_kv,
    u16* __restrict__ lnQ, u16* __restrict__ lnK, u16* __restrict__ lnV)
{
    int bx = blockIdx.x;
    if (bx < 2304) {
        int g = bx * 256 + threadIdx.x;   // float4 index, total 4*147456
        const float* src; u16* dst; int idx; float sc = 1.f;
        if (g < 147456)      { src = Wq; dst = Wqb; idx = g; sc = 0.125f; }
        else if (g < 294912) { src = Wk; dst = Wkb; idx = g - 147456; }
        else if (g < 442368) { src = Wv; dst = Wvb; idx = g - 294912; }
        else                 { src = Wo; dst = Wob; idx = g - 442368; }
        f32x4 a = ((const f32x4*)src)[idx];
        ushort4 o;
        o.x = f2bf(a[0] * sc); o.y = f2bf(a[1] * sc);
        o.z = f2bf(a[2] * sc); o.w = f2bf(a[3] * sc);
        ((ushort4*)dst)[idx] = o;
        return;
    }
    int row = (bx - 2304) * 4 + (threadIdx.x >> 6);
    int l = threadIdx.x & 63;
    const float* src = nullptr; const float* gg; const float* bb; u16* dst;
    bool zero = false;
    if (row < 2048) {
        src = tgt + (size_t)row * DDIM; gg = g_q; bb = b_q; dst = lnQ + (size_t)row * DDIM;
    } else if (row < 4096) {
        int r = row - 2048; gg = g_kv; bb = b_kv; dst = lnK + (size_t)r * DDIM;
        if (r < SREAL) src = keyb + (size_t)r * DDIM; else zero = true;
    } else {
        int r = row - 4096; gg = g_kv; bb = b_kv; dst = lnV + (size_t)r * DDIM;
        if (r < SREAL) src = valb + (size_t)r * DDIM; else zero = true;
    }
    if (zero) {
        ushort4 z; z.x = 0; z.y = 0; z.z = 0; z.w = 0;
#pragma unroll
        for (int i = 0; i < 3; i++) ((ushort4*)dst)[l + 64 * i] = z;
        return;
    }
    f32x4 a[3];
#pragma unroll
    for (int i = 0; i < 3; i++) a[i] = ((const f32x4*)src)[l + 64 * i];
    float s = 0.f;
#pragma unroll
    for (int i = 0; i < 3; i++) { s += a[i][0] + a[i][1] + a[i][2] + a[i][3]; }
#pragma unroll
    for (int m = 1; m < 64; m <<= 1) s += __shfl_xor(s, m, 64);
    float mean = s * (1.f / 768.f);
    float v = 0.f;
#pragma unroll
    for (int i = 0; i < 3; i++)
#pragma unroll
        for (int j = 0; j < 4; j++) { float d = a[i][j] - mean; v += d * d; }
#pragma unroll
    for (int m = 1; m < 64; m <<= 1) v += __shfl_xor(v, m, 64);
    float rstd = rsqrtf(v * (1.f / 768.f) + 1e-5f);
#pragma unroll
    for (int i = 0; i < 3; i++) {
        f32x4 g4 = ((const f32x4*)gg)[l + 64 * i];
        f32x4 b4 = ((const f32x4*)bb)[l + 64 * i];
        ushort4 o;
        o.x = f2bf((a[i][0] - mean) * rstd * g4[0] + b4[0]);
        o.y = f2bf((a[i][1] - mean) * rstd * g4[1] + b4[1]);
        o.z = f2bf((a[i][2] - mean) * rstd * g4[2] + b4[2]);
        o.w = f2bf((a[i][3] - mean) * rstd * g4[3] + b4[3]);
        ((ushort4*)dst)[l + 64 * i] = o;
    }
}

// ---------------- batched projection GEMM: C = A(M,768) @ W(768,768)^T + bias ----------------
// 128m x 64n tile, BK=64 double-buffered, 576 blocks (2.25/CU).
__global__ __launch_bounds__(256) void proj_kernel(
    const u16* __restrict__ lnQ, const u16* __restrict__ lnK, const u16* __restrict__ lnV,
    const u16* __restrict__ Wqb, const u16* __restrict__ Wkb, const u16* __restrict__ Wvb,
    const float* __restrict__ bq, const float* __restrict__ bk, const float* __restrict__ bv,
    u16* __restrict__ Qm, u16* __restrict__ Km, u16* __restrict__ VmT)
{
    __shared__ u16 Ash[2][128 * 64];
    __shared__ u16 Bsh[2][64 * 64];
    const u16* A; const u16* W; const float* bias; float bscale; int z = blockIdx.z;
    if (z == 0)      { A = lnQ; W = Wqb; bias = bq; bscale = 0.125f; }
    else if (z == 1) { A = lnK; W = Wkb; bias = bk; bscale = 1.f; }
    else             { A = lnV; W = Wvb; bias = bv; bscale = 1.f; }
    int n0 = blockIdx.x * 64, m0 = blockIdx.y * 128;
    int t = threadIdx.x, l = t & 63, quad = l >> 4, c16 = l & 15;
    int w = t >> 6;

    f32x4 acc[2][4];
    f32x4 zz = {0.f, 0.f, 0.f, 0.f};
#pragma unroll
    for (int mi = 0; mi < 2; mi++)
#pragma unroll
        for (int ni = 0; ni < 4; ni++) acc[mi][ni] = zz;

#pragma unroll
    for (int i = 0; i < 4; i++) {
        int ch = i * 256 + t;
        int r = ch >> 3, pc = ch & 7, jc = pc ^ (r & 7);
        async16(A + (size_t)(m0 + r) * DDIM + jc * 8, (char*)Ash[0] + ch * 16);
    }
#pragma unroll
    for (int i = 0; i < 2; i++) {
        int ch = i * 256 + t;
        int r = ch >> 3, pc = ch & 7, jc = pc ^ (r & 7);
        async16(W + (size_t)(n0 + r) * DDIM + jc * 8, (char*)Bsh[0] + ch * 16);
    }
    for (int kt = 0; kt < 12; kt++) {
        int cur = kt & 1;
        __syncthreads();
        if (kt < 11) {
            int k0 = (kt + 1) * 64;
#pragma unroll
            for (int i = 0; i < 4; i++) {
                int ch = i * 256 + t;
                int r = ch >> 3, pc = ch & 7, jc = pc ^ (r & 7);
                async16(A + (size_t)(m0 + r) * DDIM + k0 + jc * 8, (char*)Ash[cur ^ 1] + ch * 16);
            }
#pragma unroll
            for (int i = 0; i < 2; i++) {
                int ch = i * 256 + t;
                int r = ch >> 3, pc = ch & 7, jc = pc ^ (r & 7);
                async16(W + (size_t)(n0 + r) * DDIM + k0 + jc * 8, (char*)Bsh[cur ^ 1] + ch * 16);
            }
        }
#pragma unroll
        for (int kk = 0; kk < 2; kk++) {
            bf16x8 a[2], b[4];
#pragma unroll
            for (int mi = 0; mi < 2; mi++) {
                int row = w * 32 + mi * 16 + c16;
                int p = (kk * 4 + quad) ^ (row & 7);
                a[mi] = *(const bf16x8*)(Ash[cur] + row * 64 + p * 8);
            }
#pragma unroll
            for (int ni = 0; ni < 4; ni++) {
                int row = ni * 16 + c16;
                int p = (kk * 4 + quad) ^ (row & 7);
                b[ni] = *(const bf16x8*)(Bsh[cur] + row * 64 + p * 8);
            }
#pragma unroll
            for (int mi = 0; mi < 2; mi++)
#pragma unroll
                for (int ni = 0; ni < 4; ni++)
                    acc[mi][ni] = __builtin_amdgcn_mfma_f32_16x16x32_bf16(a[mi], b[ni], acc[mi][ni], 0, 0, 0);
        }
        __syncthreads();
    }
    if (z < 2) {
        u16* out = (z == 0) ? Qm : Km;
        int Mact = (z == 0) ? NQ : SREAL;
#pragma unroll
        for (int mi = 0; mi < 2; mi++)
#pragma unroll
            for (int ni = 0; ni < 4; ni++) {
                int n = n0 + ni * 16 + c16;
                float bval = bias[n] * bscale;
#pragma unroll
                for (int r = 0; r < 4; r++) {
                    int m = m0 + w * 32 + mi * 16 + quad * 4 + r;
                    float val = (m < Mact) ? (acc[mi][ni][r] + bval) : 0.f;
                    out[(size_t)m * DDIM + n] = f2bf(val);
                }
            }
    } else {
#pragma unroll
        for (int mi = 0; mi < 2; mi++)
#pragma unroll
            for (int ni = 0; ni < 4; ni++) {
                int n = n0 + ni * 16 + c16;
                float bval = bias[n];
                int mbase = m0 + w * 32 + mi * 16 + quad * 4;
                ushort4 o;
                o.x = (mbase + 0 < SREAL) ? f2bf(acc[mi][ni][0] + bval) : (u16)0;
                o.y = (mbase + 1 < SREAL) ? f2bf(acc[mi][ni][1] + bval) : (u16)0;
                o.z = (mbase + 2 < SREAL) ? f2bf(acc[mi][ni][2] + bval) : (u16)0;
                o.w = (mbase + 3 < SREAL) ? f2bf(acc[mi][ni][3] + bval) : (u16)0;
                *(ushort4*)(VmT + (size_t)n * SPAD + mbase) = o;
            }
    }
}

// ---------------- split-S flash attention: q-tile 128, dbuf K/V, 1 barrier/chunk ----------------
// grid 768 (= 3 blocks/CU exactly), XCD-swizzled. LDS 48.5KB -> 3 blocks/CU resident.
__global__ __launch_bounds__(256, 3) void attn_kernel(
    const u16* __restrict__ Qm, const u16* __restrict__ Km, const u16* __restrict__ VmT,
    const int* __restrict__ bank_mask,
    u16* __restrict__ Opart, float* __restrict__ Lpart)
{
    __shared__ __align__(16) u16 SH[24576];   // K[2]:8192 | V[2]:8192 | P:8192 (u16 counts)
    __shared__ float mk[2][64];
    u16* Kb = SH;            // [2][4096]
    u16* Vb = SH + 8192;     // [2][4096]
    u16* Psh = SH + 16384;   // [128][64]
    int b = blockIdx.x;
    int xcd = b & 7, j = b >> 3;          // j in [0,96)
    int grp = xcd * 6 + (j >> 4);         // 48 groups: grp = sp*NHEAD + h
    int qt = j & 15;
    int sp = grp / NHEAD, h = grp - sp * NHEAD;
    int q0 = qt * 128, s00 = sp * 512;
    int t = threadIdx.x, w = t >> 6, l = t & 63, quad = l >> 4, c16 = l & 15;

    bf16x8 qf[2][2];
#pragma unroll
    for (int mi = 0; mi < 2; mi++)
#pragma unroll
        for (int kk = 0; kk < 2; kk++) {
            int row = q0 + w * 32 + mi * 16 + c16;
            qf[mi][kk] = *(const bf16x8*)(Qm + (size_t)row * DDIM + h * EDIM + kk * 32 + quad * 8);
        }
    bf16x8 ones;
#pragma unroll
    for (int i = 0; i < 8; i++) ones[i] = (__bf16)1.0f;

    f32x4 zz = {0.f, 0.f, 0.f, 0.f};
    f32x4 of[2][4], ol[2];
#pragma unroll
    for (int mi = 0; mi < 2; mi++) {
#pragma unroll
        for (int nei = 0; nei < 4; nei++) of[mi][nei] = zz;
        ol[mi] = zz;
    }

    // prologue: stage chunk 0 into buffer 0
    {
        int ch0 = t, ch1 = 256 + t;
        int r0 = ch0 >> 3, jc0 = (ch0 & 7) ^ (r0 & 7);
        int r1 = ch1 >> 3, jc1 = (ch1 & 7) ^ (r1 & 7);
        async16(Km + (size_t)(s00 + r0) * DDIM + h * EDIM + jc0 * 8, (char*)Kb + ch0 * 16);
        async16(Km + (size_t)(s00 + r1) * DDIM + h * EDIM + jc1 * 8, (char*)Kb + ch1 * 16);
        async16(VmT + (size_t)(h * EDIM + r0) * SPAD + s00 + jc0 * 8, (char*)Vb + ch0 * 16);
        async16(VmT + (size_t)(h * EDIM + r1) * SPAD + s00 + jc1 * 8, (char*)Vb + ch1 * 16);
        if (t < 64) {
            int s = s00 + t;
            mk[0][t] = (s < SREAL && bank_mask[s] != 0) ? 1.f : 0.f;
        }
    }

    for (int sc = 0; sc < 8; sc++) {
        int cur = sc & 1;
        __syncthreads();   // stage(sc) landed everywhere; all compute(sc-1) done
        if (sc < 7) {
            int s0n = s00 + (sc + 1) * 64;
            char* Kd = (char*)Kb + (cur ^ 1) * 8192;
            char* Vd = (char*)Vb + (cur ^ 1) * 8192;
            int ch0 = t, ch1 = 256 + t;
            int r0 = ch0 >> 3, jc0 = (ch0 & 7) ^ (r0 & 7);
            int r1 = ch1 >> 3, jc1 = (ch1 & 7) ^ (r1 & 7);
            async16(Km + (size_t)(s0n + r0) * DDIM + h * EDIM + jc0 * 8, Kd + ch0 * 16);
            async16(Km + (size_t)(s0n + r1) * DDIM + h * EDIM + jc1 * 8, Kd + ch1 * 16);
            async16(VmT + (size_t)(h * EDIM + r0) * SPAD + s0n + jc0 * 8, Vd + ch0 * 16);
            async16(VmT + (size_t)(h * EDIM + r1) * SPAD + s0n + jc1 * 8, Vd + ch1 * 16);
            if (t < 64) {
                int s = s0n + t;
                mk[cur ^ 1][t] = (s < SREAL && bank_mask[s] != 0) ? 1.f : 0.f;
            }
        }
        const u16* Ksh = Kb + cur * 4096;
        const u16* Vsh = Vb + cur * 4096;

        // QK^T (scale folded into Wq): 32 q-rows x 64 s-cols per wave
        f32x4 sacc[2][4];
#pragma unroll
        for (int mi = 0; mi < 2; mi++)
#pragma unroll
            for (int ni = 0; ni < 4; ni++) sacc[mi][ni] = zz;
#pragma unroll
        for (int kk = 0; kk < 2; kk++) {
            bf16x8 kb[4];
#pragma unroll
            for (int ni = 0; ni < 4; ni++) {
                int row = ni * 16 + c16;
                int p = (kk * 4 + quad) ^ (row & 7);
                kb[ni] = *(const bf16x8*)(Ksh + row * 64 + p * 8);
            }
#pragma unroll
            for (int mi = 0; mi < 2; mi++)
#pragma unroll
                for (int ni = 0; ni < 4; ni++)
                    sacc[mi][ni] = __builtin_amdgcn_mfma_f32_16x16x32_bf16(qf[mi][kk], kb[ni], sacc[mi][ni], 0, 0, 0);
        }
        float m01[4];
#pragma unroll
        for (int ni = 0; ni < 4; ni++) m01[ni] = mk[cur][ni * 16 + c16];
#pragma unroll
        for (int mi = 0; mi < 2; mi++)
#pragma unroll
            for (int ni = 0; ni < 4; ni++)
#pragma unroll
                for (int r = 0; r < 4; r++)
                    sacc[mi][ni][r] = __expf(sacc[mi][ni][r]) * m01[ni];

        // write P into own wave's rows (no barrier needed: wave-private rows, in-order DS)
#pragma unroll
        for (int mi = 0; mi < 2; mi++)
#pragma unroll
            for (int ni = 0; ni < 4; ni++)
#pragma unroll
                for (int r = 0; r < 4; r++) {
                    int row = w * 32 + mi * 16 + quad * 4 + r;
                    int col = ni * 16 + c16;
                    int p = (col >> 3) ^ (row & 7);
                    Psh[row * 64 + p * 8 + (col & 7)] = f2bf(sacc[mi][ni][r]);
                }

        // O += P @ V, l += P @ 1
#pragma unroll
        for (int kk = 0; kk < 2; kk++) {
            bf16x8 pa[2], vb[4];
#pragma unroll
            for (int mi = 0; mi < 2; mi++) {
                int row = w * 32 + mi * 16 + c16;
                int p = (kk * 4 + quad) ^ (row & 7);
                pa[mi] = *(const bf16x8*)(Psh + row * 64 + p * 8);
            }
#pragma unroll
            for (int nei = 0; nei < 4; nei++) {
                int e = nei * 16 + c16;
                int p = (kk * 4 + quad) ^ (e & 7);
                vb[nei] = *(const bf16x8*)(Vsh + e * 64 + p * 8);
            }
#pragma unroll
            for (int mi = 0; mi < 2; mi++) {
#pragma unroll
                for (int nei = 0; nei < 4; nei++)
                    of[mi][nei] = __builtin_amdgcn_mfma_f32_16x16x32_bf16(pa[mi], vb[nei], of[mi][nei], 0, 0, 0);
                ol[mi] = __builtin_amdgcn_mfma_f32_16x16x32_bf16(pa[mi], ones, ol[mi], 0, 0, 0);
            }
        }
    }
    __syncthreads();   // all waves done with K/V/P before epilogue reuses SH

    // epilogue: transpose O through LDS (per-wave slice), store coalesced bf16
    float* Ost = (float*)SH + w * (16 * 68);
    int qq = l >> 2, cc = (l & 3) ^ (qq & 3);
    int base = grp * 16 + qt;
#pragma unroll
    for (int mi = 0; mi < 2; mi++) {
#pragma unroll
        for (int nei = 0; nei < 4; nei++)
#pragma unroll
            for (int r = 0; r < 4; r++)
                Ost[(quad * 4 + r) * 68 + nei * 16 + c16] = of[mi][nei][r];
        uint4 packed[2];
        u16* pk = (u16*)packed;
#pragma unroll
        for (int jj = 0; jj < 4; jj++) {
            f32x4 v = *(const f32x4*)(Ost + qq * 68 + cc * 16 + jj * 4);
            pk[jj * 4 + 0] = f2bf(v[0]); pk[jj * 4 + 1] = f2bf(v[1]);
            pk[jj * 4 + 2] = f2bf(v[2]); pk[jj * 4 + 3] = f2bf(v[3]);
        }
        u16* dst = Opart + (size_t)base * 8192 + (w * 32 + mi * 16 + qq) * 64 + cc * 16;
        *(uint4*)dst = packed[0];
        *(uint4*)(dst + 8) = packed[1];
    }
    if (c16 == 0) {
#pragma unroll
        for (int mi = 0; mi < 2; mi++)
#pragma unroll
            for (int r = 0; r < 4; r++) {
                int rin = w * 32 + mi * 16 + quad * 4 + r;
                Lpart[(size_t)base * 128 + rin] = ol[mi][r];
            }
    }
}

// ---------------- combine partials + mean-pool over TQ -> pooled (bf16), vectorized ----------------
// wave per (lq,h): lane = qrow_sub(0..7) x 8 + e-octet(0..7); uint4 loads.
__global__ __launch_bounds__(256) void combine_kernel(
    const u16* __restrict__ Opart, const float* __restrict__ Lpart,
    u16* __restrict__ pooledb)
{
    int gi = blockIdx.x * 4 + (threadIdx.x >> 6);   // 0..3071 = (lq,h)
    int l = threadIdx.x & 63;
    int lq = gi / NHEAD, h = gi - lq * NHEAD;
    int rs = l >> 3, oct = l & 7;
    int qrow = lq * 8 + rs;
    int qt = qrow >> 7, rin = qrow & 127;
    float vsum[8];
#pragma unroll
    for (int j = 0; j < 8; j++) vsum[j] = 0.f;
    float Lsum = 0.f;
#pragma unroll
    for (int sp = 0; sp < NSPLIT; sp++) {
        int base = (sp * NHEAD + h) * 16 + qt;
        uint4 pk = *(const uint4*)(Opart + (size_t)base * 8192 + rin * 64 + oct * 8);
        const u16* pu = (const u16*)&pk;
#pragma unroll
        for (int j = 0; j < 8; j++) vsum[j] += bf2f(pu[j]);
        Lsum += Lpart[(size_t)base * 128 + rin];
    }
    float inv = 1.f / Lsum;
    float c[8];
#pragma unroll
    for (int j = 0; j < 8; j++) c[j] = vsum[j] * inv;
#pragma unroll
    for (int mm = 8; mm < 64; mm <<= 1)
#pragma unroll
        for (int j = 0; j < 8; j++) c[j] += __shfl_xor(c[j], mm, 64);
    if (rs == 0) {
        uint4 packed;
        u16* pk = (u16*)&packed;
#pragma unroll
        for (int j = 0; j < 8; j++) pk[j] = f2bf(c[j] * 0.125f);
        *(uint4*)(pooledb + (size_t)lq * DDIM + h * EDIM + oct * 8) = packed;
    }
}

// ---------------- final GEMM y = pooled(256,768) @ Wo(768,768)^T + bo, bf16 MFMA ----------------
__global__ __launch_bounds__(256) void wo_kernel(
    const u16* __restrict__ pb, const u16* __restrict__ Wob,
    const float* __restrict__ bo, float* __restrict__ y)
{
    __shared__ u16 Ash[64 * 128];
    __shared__ u16 Bsh[64 * 128];
    int m0 = blockIdx.x * 64, n0 = blockIdx.y * 64;
    int t = threadIdx.x, w = t >> 6, l = t & 63, quad = l >> 4, c16 = l & 15;

    f32x4 acc[4];
    f32x4 zz = {0.f, 0.f, 0.f, 0.f};
#pragma unroll
    for (int ni = 0; ni < 4; ni++) acc[ni] = zz;

    for (int kt = 0; kt < 6; kt++) {
        int k0 = kt * 128;
#pragma unroll
        for (int i = 0; i < 4; i++) {
            int ch = i * 256 + t;
            int r = ch >> 4, pc = ch & 15, jc = pc ^ (r & 15);
            async16(pb + (size_t)(m0 + r) * DDIM + k0 + jc * 8, (char*)Ash + ch * 16);
            async16(Wob + (size_t)(n0 + r) * DDIM + k0 + jc * 8, (char*)Bsh + ch * 16);
        }
        __syncthreads();
#pragma unroll
        for (int kk = 0; kk < 4; kk++) {
            int p = (kk * 4 + quad) ^ c16;
            bf16x8 a = *(const bf16x8*)(Ash + (w * 16 + c16) * 128 + p * 8);
            bf16x8 b[4];
#pragma unroll
            for (int ni = 0; ni < 4; ni++)
                b[ni] = *(const bf16x8*)(Bsh + (ni * 16 + c16) * 128 + p * 8);
#pragma unroll
            for (int ni = 0; ni < 4; ni++)
                acc[ni] = __builtin_amdgcn_mfma_f32_16x16x32_bf16(a, b[ni], acc[ni], 0, 0, 0);
        }
        __syncthreads();
    }
#pragma unroll
    for (int ni = 0; ni < 4; ni++) {
        int n = n0 + ni * 16 + c16;
        float bval = bo[n];
#pragma unroll
        for (int r = 0; r < 4; r++) {
            int m = m0 + w * 16 + quad * 4 + r;
            y[(size_t)m * DDIM + n] = acc[ni][r] + bval;
        }
    }
}

extern "C" void kernel_launch(void* const* d_in, const int* in_sizes, int n_in,
                              void* d_out, int out_size, void* d_ws, size_t ws_size,
                              hipStream_t stream)
{
    const float* tgt     = (const float*)d_in[0];
    const float* keyb    = (const float*)d_in[1];
    const float* valb    = (const float*)d_in[2];
    const int*   mask    = (const int*)d_in[3];
    const float* Wq      = (const float*)d_in[4];
    const float* bq      = (const float*)d_in[5];
    const float* Wk      = (const float*)d_in[6];
    const float* bk      = (const float*)d_in[7];
    const float* Wv      = (const float*)d_in[8];
    const float* bv      = (const float*)d_in[9];
    const float* Wo      = (const float*)d_in[10];
    const float* bo      = (const float*)d_in[11];
    const float* g_q     = (const float*)d_in[12];
    const float* beta_q  = (const float*)d_in[13];
    const float* g_kv    = (const float*)d_in[14];
    const float* beta_kv = (const float*)d_in[15];
    float* y = (float*)d_out;

    char* ws = (char*)d_ws;
    // persistent:
    u16* Qm  = (u16*)(ws + 0);           // 3,145,728
    u16* Km  = (u16*)(ws + 3145728);     // 3,145,728
    u16* VmT = (u16*)(ws + 6291456);     // 3,145,728
    u16* Wob = (u16*)(ws + 9437184);     // 1,179,648
    // phase A (dead after proj_kernel):
    u16* lnQ = (u16*)(ws + 10616832);
    u16* lnK = (u16*)(ws + 13762560);
    u16* lnV = (u16*)(ws + 16908288);
    u16* Wqb = (u16*)(ws + 20054016);
    u16* Wkb = (u16*)(ws + 21233664);
    u16* Wvb = (u16*)(ws + 22413312);    // ends 23,592,960
    // phase B (aliases phase A region):
    u16*   Opart   = (u16*)(ws + 10616832);   // 12,582,912
    float* Lpart   = (float*)(ws + 23592960); // 393,216
    u16*   pooledb = (u16*)(ws + 23986176);   // 393,216

    hipLaunchKernelGGL(prep_kernel, dim3(3840), dim3(256), 0, stream,
                       Wq, Wk, Wv, Wo, Wqb, Wkb, Wvb, Wob,
                       tgt, keyb, valb, g_q, beta_q, g_kv, beta_kv, lnQ, lnK, lnV);
    hipLaunchKernelGGL(proj_kernel, dim3(12, 16, 3), dim3(256), 0, stream,
                       lnQ, lnK, lnV, Wqb, Wkb, Wvb, bq, bk, bv, Qm, Km, VmT);
    hipLaunchKernelGGL(attn_kernel, dim3(768), dim3(256), 0, stream,
                       Qm, Km, VmT, mask, Opart, Lpart);
    hipLaunchKernelGGL(combine_kernel, dim3(768), dim3(256), 0, stream,
                       Opart, Lpart, pooledb);
    hipLaunchKernelGGL(wo_kernel, dim3(4, 12), dim3(256), 0, stream,
                       pooledb, Wob, bo, y);
}